// Round 1
// baseline (2883.225 us; speedup 1.0000x reference)
//
#include <hip/hip_runtime.h>
#include <math.h>

namespace {
constexpr int N_ROWS = 4096;
constexpr int D      = 1024;
constexpr int D4     = D / 4;
constexpr int CUT0   = 2000;
constexpr int CUT1   = 10000;
constexpr int HEAD_M = CUT0 + 2;   // 2002
constexpr int RPB    = 8;          // rows per block
}

// ---------------- utility kernels ----------------

__global__ void zero2_k(int* c) { c[0] = 0; c[1] = 0; }

__global__ void classify_k(const int* __restrict__ target, int* __restrict__ cnt,
                           int* __restrict__ list0, int* __restrict__ list1) {
  int i = blockIdx.x * 256 + threadIdx.x;
  if (i >= N_ROWS) return;
  int t = target[i];
  if (t >= CUT0 && t < CUT1)      list0[atomicAdd(&cnt[0], 1)] = i;
  else if (t >= CUT1)             list1[atomicAdd(&cnt[1], 1)] = i;
}

// ---------------- head: fused GEMM + online LSE + gather ----------------

__global__ __launch_bounds__(256) void head_k(
    const float* __restrict__ hidden, const int* __restrict__ target,
    const float* __restrict__ head_w, float* __restrict__ out) {
  __shared__ float4 hs[RPB][D4];                  // 32 KB staged hidden rows
  __shared__ float red_m[RPB][4], red_s[RPB][4], gat[RPB];
  const int tid  = threadIdx.x;
  const int row0 = blockIdx.x * RPB;
  const float4* h4 = (const float4*)hidden;
#pragma unroll
  for (int r = 0; r < RPB; ++r)
    hs[r][tid] = h4[(size_t)(row0 + r) * D4 + tid];

  int jt[RPB];
#pragma unroll
  for (int r = 0; r < RPB; ++r) {
    int t = target[row0 + r];
    jt[r] = (t < 0) ? 0 : (t < CUT0 ? t : (t < CUT1 ? CUT0 : CUT0 + 1));
  }
  __syncthreads();

  float tm[RPB], ts[RPB];
#pragma unroll
  for (int r = 0; r < RPB; ++r) { tm[r] = -1e30f; ts[r] = 0.f; }

  for (int j = tid; j < HEAD_M; j += 256) {
    const float4* w = (const float4*)(head_w + (size_t)j * D);
    float acc[RPB];
#pragma unroll
    for (int r = 0; r < RPB; ++r) acc[r] = 0.f;
    for (int k = 0; k < D4; ++k) {
      float4 wv = w[k];
#pragma unroll
      for (int r = 0; r < RPB; ++r) {
        float4 h = hs[r][k];
        acc[r] = fmaf(h.x, wv.x, fmaf(h.y, wv.y, fmaf(h.z, wv.z, fmaf(h.w, wv.w, acc[r]))));
      }
    }
#pragma unroll
    for (int r = 0; r < RPB; ++r) {
      float v = acc[r];
      if (j == jt[r]) gat[r] = v;
      float nm = fmaxf(tm[r], v);
      ts[r] = ts[r] * __expf(tm[r] - nm) + __expf(v - nm);
      tm[r] = nm;
    }
  }

  // wave reduce then cross-wave reduce of (max, sumexp)
#pragma unroll
  for (int r = 0; r < RPB; ++r) {
    float m = tm[r], s = ts[r];
    for (int off = 32; off; off >>= 1) {
      float mo = __shfl_xor(m, off);
      float so = __shfl_xor(s, off);
      float nm = fmaxf(m, mo);
      s = s * __expf(m - nm) + so * __expf(mo - nm);
      m = nm;
    }
    if ((tid & 63) == 0) { red_m[r][tid >> 6] = m; red_s[r][tid >> 6] = s; }
  }
  __syncthreads();
  if (tid < RPB) {
    float m = red_m[tid][0], s = red_s[tid][0];
#pragma unroll
    for (int w = 1; w < 4; ++w) {
      float mo = red_m[tid][w], so = red_s[tid][w];
      float nm = fmaxf(m, mo);
      s = s * __expf(m - nm) + so * __expf(mo - nm);
      m = nm;
    }
    float lse = m + __logf(s);
    int row = row0 + tid;
    int t = target[row];
    out[row] = (t < 0) ? 0.f : (gat[tid] - lse);
  }
}

// ---------------- tail clusters: proj + fused GEMM + LSE, compacted rows ----

template <int M, int K>
__global__ __launch_bounds__(256) void tail_k(
    const float* __restrict__ hidden, const int* __restrict__ target,
    const float* __restrict__ proj, const float* __restrict__ tw,
    const int* __restrict__ list, const int* __restrict__ cnt_p,
    int lo, float* __restrict__ out) {
  __shared__ float4 hs[RPB][D4];                  // 32 KB
  __shared__ __align__(16) float zz[RPB][K];      // projected rows
  __shared__ float red_m[RPB][4], red_s[RPB][4], gat[RPB];
  const int n = *cnt_p;
  const int base = blockIdx.x * RPB;
  if (base >= n) return;
  const int tid = threadIdx.x;

  int rows[RPB];
#pragma unroll
  for (int r = 0; r < RPB; ++r) {
    int idx = base + r;
    rows[r] = list[idx < n ? idx : base];  // duplicate a valid row for the tail
  }
  const float4* h4 = (const float4*)hidden;
#pragma unroll
  for (int r = 0; r < RPB; ++r)
    hs[r][tid] = h4[(size_t)rows[r] * D4 + tid];

  int jt[RPB];
#pragma unroll
  for (int r = 0; r < RPB; ++r) jt[r] = target[rows[r]] - lo;
  __syncthreads();

  // low-rank projection: thread j < K computes z[r][j]
  if (tid < K) {
    const float4* p = (const float4*)(proj + (size_t)tid * D);
    float acc[RPB];
#pragma unroll
    for (int r = 0; r < RPB; ++r) acc[r] = 0.f;
    for (int k = 0; k < D4; ++k) {
      float4 pv = p[k];
#pragma unroll
      for (int r = 0; r < RPB; ++r) {
        float4 h = hs[r][k];
        acc[r] = fmaf(h.x, pv.x, fmaf(h.y, pv.y, fmaf(h.z, pv.z, fmaf(h.w, pv.w, acc[r]))));
      }
    }
#pragma unroll
    for (int r = 0; r < RPB; ++r) zz[r][tid] = acc[r];
  }
  __syncthreads();

  constexpr int K4 = K / 4;
  float tm[RPB], ts[RPB];
#pragma unroll
  for (int r = 0; r < RPB; ++r) { tm[r] = -1e30f; ts[r] = 0.f; }

  for (int j = tid; j < M; j += 256) {
    const float4* w = (const float4*)(tw + (size_t)j * K);
    float acc[RPB];
#pragma unroll
    for (int r = 0; r < RPB; ++r) acc[r] = 0.f;
    for (int k = 0; k < K4; ++k) {
      float4 wv = w[k];
#pragma unroll
      for (int r = 0; r < RPB; ++r) {
        float4 h = ((const float4*)zz[r])[k];
        acc[r] = fmaf(h.x, wv.x, fmaf(h.y, wv.y, fmaf(h.z, wv.z, fmaf(h.w, wv.w, acc[r]))));
      }
    }
#pragma unroll
    for (int r = 0; r < RPB; ++r) {
      float v = acc[r];
      if (j == jt[r]) gat[r] = v;
      float nm = fmaxf(tm[r], v);
      ts[r] = ts[r] * __expf(tm[r] - nm) + __expf(v - nm);
      tm[r] = nm;
    }
  }

#pragma unroll
  for (int r = 0; r < RPB; ++r) {
    float m = tm[r], s = ts[r];
    for (int off = 32; off; off >>= 1) {
      float mo = __shfl_xor(m, off);
      float so = __shfl_xor(s, off);
      float nm = fmaxf(m, mo);
      s = s * __expf(m - nm) + so * __expf(mo - nm);
      m = nm;
    }
    if ((tid & 63) == 0) { red_m[r][tid >> 6] = m; red_s[r][tid >> 6] = s; }
  }
  __syncthreads();
  if (tid < RPB) {
    float m = red_m[tid][0], s = red_s[tid][0];
#pragma unroll
    for (int w = 1; w < 4; ++w) {
      float mo = red_m[tid][w], so = red_s[tid][w];
      float nm = fmaxf(m, mo);
      s = s * __expf(m - nm) + so * __expf(mo - nm);
      m = nm;
    }
    float lse = m + __logf(s);
    int idx = base + tid;
    if (idx < n) {
      int row = list[idx];
      out[row] += gat[tid] - lse;   // add tail log-prob to head cluster log-prob
    }
  }
}

// ---------------- final loss reduction ----------------

__global__ __launch_bounds__(256) void loss_k(const float* __restrict__ out,
                                              const int* __restrict__ target,
                                              float* __restrict__ loss) {
  __shared__ float ssum[256];
  __shared__ int scnt[256];
  float s = 0.f; int c = 0;
  for (int i = threadIdx.x; i < N_ROWS; i += 256) {
    s += out[i];
    if (target[i] >= 0) c++;
  }
  ssum[threadIdx.x] = s; scnt[threadIdx.x] = c;
  __syncthreads();
  for (int off = 128; off; off >>= 1) {
    if (threadIdx.x < off) {
      ssum[threadIdx.x] += ssum[threadIdx.x + off];
      scnt[threadIdx.x] += scnt[threadIdx.x + off];
    }
    __syncthreads();
  }
  if (threadIdx.x == 0) {
    int nv = scnt[0];
    loss[0] = (nv > 0) ? (-ssum[0] / (float)nv) : 0.f;
  }
}

// ---------------- launch ----------------

extern "C" void kernel_launch(void* const* d_in, const int* in_sizes, int n_in,
                              void* d_out, int out_size, void* d_ws, size_t ws_size,
                              hipStream_t stream) {
  const float* hidden = (const float*)d_in[0];
  const int*   target = (const int*)d_in[1];
  const float* head_w = (const float*)d_in[2];
  const float* proj0  = (const float*)d_in[3];
  const float* tail0  = (const float*)d_in[4];
  const float* proj1  = (const float*)d_in[5];
  const float* tail1  = (const float*)d_in[6];
  float* out = (float*)d_out;

  int* cnt   = (int*)d_ws;           // [2] counters
  int* list0 = cnt + 2;              // [N_ROWS]
  int* list1 = cnt + 2 + N_ROWS;     // [N_ROWS]

  zero2_k<<<1, 1, 0, stream>>>(cnt);
  classify_k<<<N_ROWS / 256, 256, 0, stream>>>(target, cnt, list0, list1);
  head_k<<<N_ROWS / RPB, 256, 0, stream>>>(hidden, target, head_w, out);
  tail_k<8000, 256><<<N_ROWS / RPB, 256, 0, stream>>>(hidden, target, proj0, tail0,
                                                      list0, &cnt[0], CUT0, out);
  tail_k<40257, 64><<<N_ROWS / RPB, 256, 0, stream>>>(hidden, target, proj1, tail1,
                                                      list1, &cnt[1], CUT1, out);
  loss_k<<<1, 256, 0, stream>>>(out, target, out + N_ROWS);
}

// Round 2
// 343.706 us; speedup vs baseline: 8.3886x; 8.3886x over previous
//
#include <hip/hip_runtime.h>
#include <math.h>

using f32x4  = __attribute__((ext_vector_type(4))) float;
using bf16x8 = __attribute__((ext_vector_type(8))) short;

namespace {
constexpr int N_ROWS = 4096;
constexpr int D      = 1024;
constexpr int CUT0   = 2000, CUT1 = 10000, VTOT = 50257;
constexpr int HM  = 2002,        HMP  = 2016;   // head cols, padded to x16
constexpr int T0M = 8000,        T0MP = 8000;   // cluster0 cols (already x16)
constexpr int T1M = VTOT - CUT1, T1MP = 40272;  // 40257 -> padded
}

__device__ __forceinline__ unsigned short f2bf(float x) {
  unsigned u = __builtin_bit_cast(unsigned, x);
  u += 0x7FFFu + ((u >> 16) & 1u);
  return (unsigned short)(u >> 16);
}
__device__ __forceinline__ float bf2f(unsigned short b) {
  unsigned u = ((unsigned)b) << 16;
  return __builtin_bit_cast(float, u);
}

// ---------------- prep ----------------

__global__ void zero2_k(int* c) { c[0] = 0; c[1] = 0; }

__global__ void classify_k(const int* __restrict__ tgt, int* __restrict__ cnt,
                           int* __restrict__ l0, int* __restrict__ l1,
                           int* __restrict__ pos) {
  int i = blockIdx.x * 256 + threadIdx.x;
  if (i >= N_ROWS) return;
  int t = tgt[i];
  if (t >= CUT0 && t < CUT1) { int p = atomicAdd(&cnt[0], 1); l0[p] = i; pos[i] = p; }
  else if (t >= CUT1)        { int p = atomicAdd(&cnt[1], 1); l1[p] = i; pos[i] = p; }
}

// fp32 -> bf16 (RNE), zero-fill pad region. nsrc, ncap multiples of 4.
__global__ void convert_k(const float* __restrict__ src, unsigned short* __restrict__ dst,
                          int nsrc, int ncap) {
  int i = (blockIdx.x * 256 + threadIdx.x) * 4;
  if (i >= ncap) return;
  ushort4 o;
  if (i < nsrc) {
    float4 f = *(const float4*)(src + i);
    o.x = f2bf(f.x); o.y = f2bf(f.y); o.z = f2bf(f.z); o.w = f2bf(f.w);
  } else {
    o.x = o.y = o.z = o.w = 0;
  }
  *(ushort4*)(dst + i) = o;
}

// ---------------- z = gather(hidden) @ proj^T  (bf16 out) ----------------

template <int KC>
__global__ __launch_bounds__(256) void z_k(const float* __restrict__ hidden,
    const unsigned short* __restrict__ pbf, const int* __restrict__ list,
    const int* __restrict__ cntp, unsigned short* __restrict__ z) {
  int n = *cntp;
  int rowbase = blockIdx.x * 16;
  if (rowbase >= n) return;
  int tid = threadIdx.x, w = tid >> 6, l = tid & 63;
  int lr = l & 15, kg = l >> 4;
  int srcrow = list[min(rowbase + lr, n - 1)];
  const float* ha = hidden + (size_t)srcrow * D + kg * 8;
  for (int t = w; t < KC / 16; t += 4) {
    const unsigned short* pb = pbf + (size_t)(t * 16 + lr) * D + kg * 8;
    f32x4 acc = {0.f, 0.f, 0.f, 0.f};
    for (int kc = 0; kc < D / 32; ++kc) {
      float4 h0 = *(const float4*)(ha + kc * 32);
      float4 h1 = *(const float4*)(ha + kc * 32 + 4);
      bf16x8 a;
      a[0] = f2bf(h0.x); a[1] = f2bf(h0.y); a[2] = f2bf(h0.z); a[3] = f2bf(h0.w);
      a[4] = f2bf(h1.x); a[5] = f2bf(h1.y); a[6] = f2bf(h1.z); a[7] = f2bf(h1.w);
      bf16x8 b = *(const bf16x8*)(pb + kc * 32);
      acc = __builtin_amdgcn_mfma_f32_16x16x32_bf16(a, b, acc, 0, 0, 0);
    }
    int col = t * 16 + lr;                 // C: col = lane&15
    for (int v = 0; v < 4; ++v) {          //    row = (lane>>4)*4 + v
      int idx = rowbase + kg * 4 + v;
      if (idx < n) z[(size_t)idx * KC + col] = f2bf(acc[v]);
    }
  }
}

// ---------------- head: 32 rows x col-slice, LDS-swizzled A ----------------

__global__ __launch_bounds__(256) void head_k(const float* __restrict__ hidden,
    const unsigned short* __restrict__ hwbf, float* __restrict__ hs_part) {
  __shared__ char Ab[32 * 2048];           // 64 KB bf16, XOR-swizzled
  __shared__ float red[4][32];
  int bx = blockIdx.x;
  int rt = bx >> 1, slice = bx & 1;
  int rows = rt * 32;
  int tid = threadIdx.x, w = tid >> 6, l = tid & 63;

  const float4* h4 = (const float4*)hidden;
#pragma unroll
  for (int j = 0; j < 16; ++j) {
    int c = j * 256 + tid;
    int row = c >> 7, k8 = (c & 127) * 8;
    size_t fo = ((size_t)(rows + row) * D + k8) / 4;
    float4 f0 = h4[fo], f1 = h4[fo + 1];
    bf16x8 o;
    o[0] = f2bf(f0.x); o[1] = f2bf(f0.y); o[2] = f2bf(f0.z); o[3] = f2bf(f0.w);
    o[4] = f2bf(f1.x); o[5] = f2bf(f1.y); o[6] = f2bf(f1.z); o[7] = f2bf(f1.w);
    int addr = (row * 2048 + k8 * 2) ^ ((row & 7) << 4);
    *(bf16x8*)(Ab + addr) = o;
  }
  __syncthreads();

  int lr = l & 15, kg = l >> 4;
  float s[8];
#pragma unroll
  for (int i = 0; i < 8; ++i) s[i] = 0.f;

  int t0 = slice * 63, t1 = t0 + 63;       // 126 col-tiles total (2016 cols)
  for (int tt = t0 + w; tt < t1; tt += 4) {
    int col = tt * 16 + lr;
    const bf16x8* bp = (const bf16x8*)(hwbf + (size_t)col * D + kg * 8);
    f32x4 acc0 = {0.f, 0.f, 0.f, 0.f}, acc1 = acc0;
#pragma unroll 8
    for (int kc = 0; kc < 32; ++kc) {
      int a0a = ((lr)*2048 + kc * 64 + kg * 16) ^ ((lr & 7) << 4);
      int a1a = ((16 + lr) * 2048 + kc * 64 + kg * 16) ^ ((lr & 7) << 4);
      bf16x8 a0 = *(const bf16x8*)(Ab + a0a);
      bf16x8 a1 = *(const bf16x8*)(Ab + a1a);
      bf16x8 b = bp[kc * 4];
      acc0 = __builtin_amdgcn_mfma_f32_16x16x32_bf16(a0, b, acc0, 0, 0, 0);
      acc1 = __builtin_amdgcn_mfma_f32_16x16x32_bf16(a1, b, acc1, 0, 0, 0);
    }
    bool in = col < HM;
#pragma unroll
    for (int v = 0; v < 4; ++v) {
      s[v]     += in ? __expf(acc0[v]) : 0.f;
      s[4 + v] += in ? __expf(acc1[v]) : 0.f;
    }
  }
#pragma unroll
  for (int off = 1; off < 16; off <<= 1)
#pragma unroll
    for (int i = 0; i < 8; ++i) s[i] += __shfl_xor(s[i], off);
  if (lr == 0) {
#pragma unroll
    for (int v = 0; v < 4; ++v) {
      red[w][kg * 4 + v]      = s[v];
      red[w][16 + kg * 4 + v] = s[4 + v];
    }
  }
  __syncthreads();
  if (tid < 32)
    hs_part[slice * N_ROWS + rows + tid] =
        red[0][tid] + red[1][tid] + red[2][tid] + red[3][tid];
}

// ---------------- tails: 32 compacted rows, A-frags in registers ----------

template <int M, int MP, int K>
__global__ __launch_bounds__(256) void tail_k(const unsigned short* __restrict__ z,
    const unsigned short* __restrict__ twbf, const int* __restrict__ list,
    const int* __restrict__ cntp, float* __restrict__ ts_part) {
  constexpr int TILES = MP / 16;
  constexpr int ST = (TILES + 3) / 4;
  constexpr int NK = K / 32;
  __shared__ float red[4][32];
  int n = *cntp;
  int bx = blockIdx.x;
  int rt = bx >> 2, slice = bx & 3;
  int rowbase = rt * 32;
  if (rowbase >= n) return;
  int tid = threadIdx.x, w = tid >> 6, l = tid & 63;
  int lr = l & 15, kg = l >> 4;

  bf16x8 a0[NK], a1[NK];
  {
    int i0 = min(rowbase + lr, n - 1), i1 = min(rowbase + 16 + lr, n - 1);
#pragma unroll
    for (int kc = 0; kc < NK; ++kc) {
      a0[kc] = *(const bf16x8*)(z + (size_t)i0 * K + kc * 32 + kg * 8);
      a1[kc] = *(const bf16x8*)(z + (size_t)i1 * K + kc * 32 + kg * 8);
    }
  }
  float s[8];
#pragma unroll
  for (int i = 0; i < 8; ++i) s[i] = 0.f;

  int t0 = slice * ST, t1 = min(t0 + ST, TILES);
  for (int tt = t0 + w; tt < t1; tt += 4) {
    int col = tt * 16 + lr;
    const bf16x8* bp = (const bf16x8*)(twbf + (size_t)col * K + kg * 8);
    f32x4 acc0 = {0.f, 0.f, 0.f, 0.f}, acc1 = acc0;
#pragma unroll
    for (int kc = 0; kc < NK; ++kc) {
      bf16x8 b = bp[kc * 4];
      acc0 = __builtin_amdgcn_mfma_f32_16x16x32_bf16(a0[kc], b, acc0, 0, 0, 0);
      acc1 = __builtin_amdgcn_mfma_f32_16x16x32_bf16(a1[kc], b, acc1, 0, 0, 0);
    }
    bool in = col < M;
#pragma unroll
    for (int v = 0; v < 4; ++v) {
      s[v]     += in ? __expf(acc0[v]) : 0.f;
      s[4 + v] += in ? __expf(acc1[v]) : 0.f;
    }
  }
#pragma unroll
  for (int off = 1; off < 16; off <<= 1)
#pragma unroll
    for (int i = 0; i < 8; ++i) s[i] += __shfl_xor(s[i], off);
  if (lr == 0) {
#pragma unroll
    for (int v = 0; v < 4; ++v) {
      red[w][kg * 4 + v]      = s[v];
      red[w][16 + kg * 4 + v] = s[4 + v];
    }
  }
  __syncthreads();
  if (tid < 32) {
    int idx = rowbase + tid;
    if (idx < n)
      ts_part[slice * N_ROWS + list[idx]] =
          red[0][tid] + red[1][tid] + red[2][tid] + red[3][tid];
  }
}

// ---------------- finalize: gather target logits + combine LSE ------------

__global__ __launch_bounds__(256) void finalize_k(const float* __restrict__ hidden,
    const int* __restrict__ tgt, const float* __restrict__ head_w,
    const float* __restrict__ tail0, const float* __restrict__ tail1,
    const unsigned short* __restrict__ z0, const unsigned short* __restrict__ z1,
    const int* __restrict__ pos, const float* __restrict__ hs_part,
    const float* __restrict__ ts_part, float* __restrict__ out) {
  int w = threadIdx.x >> 6, l = threadIdx.x & 63;
  int row = blockIdx.x * 4 + w;
  int t = tgt[row];
  int jt = t < 0 ? 0 : (t < CUT0 ? t : (t < CUT1 ? CUT0 : CUT0 + 1));
  const float4* h4 = (const float4*)(hidden + (size_t)row * D);
  const float4* w4 = (const float4*)(head_w + (size_t)jt * D);
  float acc = 0.f;
#pragma unroll
  for (int j = 0; j < 4; ++j) {
    float4 a = h4[l + 64 * j], b = w4[l + 64 * j];
    acc += a.x * b.x + a.y * b.y + a.z * b.z + a.w * b.w;
  }
#pragma unroll
  for (int off = 32; off; off >>= 1) acc += __shfl_xor(acc, off);
  float val = acc - __logf(hs_part[row] + hs_part[N_ROWS + row]);
  if (t >= CUT0) {
    int p = pos[row];
    float ta = 0.f;
    if (t < CUT1) {
      const unsigned short* zr = z0 + (size_t)p * 256;
      const float* tw = tail0 + (size_t)(t - CUT0) * 256;
#pragma unroll
      for (int j = 0; j < 4; ++j) ta += bf2f(zr[l + 64 * j]) * tw[l + 64 * j];
    } else {
      const unsigned short* zr = z1 + (size_t)p * 64;
      const float* tw = tail1 + (size_t)(t - CUT1) * 64;
      ta = bf2f(zr[l]) * tw[l];
    }
#pragma unroll
    for (int off = 32; off; off >>= 1) ta += __shfl_xor(ta, off);
    float lt = ts_part[row] + ts_part[N_ROWS + row] +
               ts_part[2 * N_ROWS + row] + ts_part[3 * N_ROWS + row];
    val += ta - __logf(lt);
  }
  if (l == 0) out[row] = (t < 0) ? 0.f : val;
}

// ---------------- loss ----------------

__global__ __launch_bounds__(256) void loss_k(const float* __restrict__ out,
                                              const int* __restrict__ target,
                                              float* __restrict__ loss) {
  __shared__ float ssum[256];
  __shared__ int scnt[256];
  float s = 0.f; int c = 0;
  for (int i = threadIdx.x; i < N_ROWS; i += 256) {
    s += out[i];
    if (target[i] >= 0) c++;
  }
  ssum[threadIdx.x] = s; scnt[threadIdx.x] = c;
  __syncthreads();
  for (int off = 128; off; off >>= 1) {
    if (threadIdx.x < off) {
      ssum[threadIdx.x] += ssum[threadIdx.x + off];
      scnt[threadIdx.x] += scnt[threadIdx.x + off];
    }
    __syncthreads();
  }
  if (threadIdx.x == 0) {
    int nv = scnt[0];
    loss[0] = (nv > 0) ? (-ssum[0] / (float)nv) : 0.f;
  }
}

// ---------------- launch ----------------

extern "C" void kernel_launch(void* const* d_in, const int* in_sizes, int n_in,
                              void* d_out, int out_size, void* d_ws, size_t ws_size,
                              hipStream_t stream) {
  const float* hidden = (const float*)d_in[0];
  const int*   target = (const int*)d_in[1];
  const float* head_w = (const float*)d_in[2];
  const float* proj0  = (const float*)d_in[3];
  const float* tail0  = (const float*)d_in[4];
  const float* proj1  = (const float*)d_in[5];
  const float* tail1  = (const float*)d_in[6];
  float* out = (float*)d_out;

  char* wp = (char*)d_ws;
  auto alloc = [&](size_t bytes) {
    char* p = wp;
    wp += (bytes + 255) & ~(size_t)255;
    return p;
  };
  int* cnt   = (int*)alloc(8);
  int* list0 = (int*)alloc(N_ROWS * 4);
  int* list1 = (int*)alloc(N_ROWS * 4);
  int* pos   = (int*)alloc(N_ROWS * 4);
  unsigned short* hwbf = (unsigned short*)alloc((size_t)HMP * D * 2);
  unsigned short* t0bf = (unsigned short*)alloc((size_t)T0MP * 256 * 2);
  unsigned short* t1bf = (unsigned short*)alloc((size_t)T1MP * 64 * 2);
  unsigned short* p0bf = (unsigned short*)alloc((size_t)256 * D * 2);
  unsigned short* p1bf = (unsigned short*)alloc((size_t)64 * D * 2);
  unsigned short* z0   = (unsigned short*)alloc((size_t)N_ROWS * 256 * 2);
  unsigned short* z1   = (unsigned short*)alloc((size_t)N_ROWS * 64 * 2);
  float* hs_part = (float*)alloc(2 * N_ROWS * 4);
  float* ts_part = (float*)alloc(4 * N_ROWS * 4);

  zero2_k<<<1, 1, 0, stream>>>(cnt);
  classify_k<<<N_ROWS / 256, 256, 0, stream>>>(target, cnt, list0, list1, pos);
  auto cgrid = [](int cap) { return (cap / 4 + 255) / 256; };
  convert_k<<<cgrid(HMP * D), 256, 0, stream>>>(head_w, hwbf, HM * D, HMP * D);
  convert_k<<<cgrid(T0MP * 256), 256, 0, stream>>>(tail0, t0bf, T0M * 256, T0MP * 256);
  convert_k<<<cgrid(T1MP * 64), 256, 0, stream>>>(tail1, t1bf, T1M * 64, T1MP * 64);
  convert_k<<<cgrid(256 * D), 256, 0, stream>>>(proj0, p0bf, 256 * D, 256 * D);
  convert_k<<<cgrid(64 * D), 256, 0, stream>>>(proj1, p1bf, 64 * D, 64 * D);
  z_k<256><<<N_ROWS / 16, 256, 0, stream>>>(hidden, p0bf, list0, cnt + 0, z0);
  z_k<64><<<N_ROWS / 16, 256, 0, stream>>>(hidden, p1bf, list1, cnt + 1, z1);
  head_k<<<(N_ROWS / 32) * 2, 256, 0, stream>>>(hidden, hwbf, hs_part);
  tail_k<T0M, T0MP, 256><<<(N_ROWS / 32) * 4, 256, 0, stream>>>(z0, t0bf, list0, cnt + 0, ts_part);
  tail_k<T1M, T1MP, 64><<<(N_ROWS / 32) * 4, 256, 0, stream>>>(z1, t1bf, list1, cnt + 1, ts_part);
  finalize_k<<<N_ROWS / 4, 256, 0, stream>>>(hidden, target, head_w, tail0, tail1,
                                             z0, z1, pos, hs_part, ts_part, out);
  loss_k<<<1, 256, 0, stream>>>(out, target, out + N_ROWS);
}

// Round 3
// 241.795 us; speedup vs baseline: 11.9243x; 1.4215x over previous
//
#include <hip/hip_runtime.h>
#include <math.h>

using f32x4  = __attribute__((ext_vector_type(4))) float;
using bf16x8 = __attribute__((ext_vector_type(8))) short;

namespace {
constexpr int N_ROWS = 4096;
constexpr int D      = 1024;
constexpr int CUT0   = 2000, CUT1 = 10000, VTOT = 50257;
constexpr int HM   = 2002;                 // head cols (2000 + 2 cluster)
constexpr int HMP  = 2048;                 // padded head cols (pad = 46)
constexpr int T0M  = 8000,              T0MP = 8000;    // pad 0
constexpr int T1M  = VTOT - CUT1;                        // 40257
constexpr int T1MP = 40272;                              // pad 15
constexpr float LOG2E = 1.4426950408889634f;
}

__device__ __forceinline__ unsigned short f2bf(float x) {
  unsigned u = __builtin_bit_cast(unsigned, x);
  u += 0x7FFFu + ((u >> 16) & 1u);
  return (unsigned short)(u >> 16);
}
__device__ __forceinline__ float bf2f(unsigned short b) {
  unsigned u = ((unsigned)b) << 16;
  return __builtin_bit_cast(float, u);
}

// ---------------- prep ----------------

__global__ void zero2_k(int* c) { c[0] = 0; c[1] = 0; }

__global__ void classify_k(const int* __restrict__ tgt, int* __restrict__ cnt,
                           int* __restrict__ l0, int* __restrict__ l1,
                           int* __restrict__ pos) {
  int i = blockIdx.x * 256 + threadIdx.x;
  if (i >= N_ROWS) return;
  int t = tgt[i];
  if (t >= CUT0 && t < CUT1) { int p = atomicAdd(&cnt[0], 1); l0[p] = i; pos[i] = p; }
  else if (t >= CUT1)        { int p = atomicAdd(&cnt[1], 1); l1[p] = i; pos[i] = p; }
}

// fp32 -> bf16 (RNE) with scale, zero-fill pad region.
__global__ void convert_k(const float* __restrict__ src, unsigned short* __restrict__ dst,
                          int nsrc, int ncap, float scale) {
  int i = (blockIdx.x * 256 + threadIdx.x) * 4;
  if (i >= ncap) return;
  ushort4 o;
  if (i < nsrc) {
    float4 f = *(const float4*)(src + i);
    o.x = f2bf(f.x * scale); o.y = f2bf(f.y * scale);
    o.z = f2bf(f.z * scale); o.w = f2bf(f.w * scale);
  } else {
    o.x = o.y = o.z = o.w = 0;
  }
  *(ushort4*)(dst + i) = o;
}

// ---------------- z = gather(hidden) @ proj^T  (bf16 out, unscaled) -------

template <int KC>
__global__ __launch_bounds__(256) void z_k(const float* __restrict__ hidden,
    const unsigned short* __restrict__ pbf, const int* __restrict__ list,
    const int* __restrict__ cntp, unsigned short* __restrict__ z) {
  int n = *cntp;
  int rowbase = blockIdx.x * 16;
  if (rowbase >= n) return;
  int tid = threadIdx.x, w = tid >> 6, l = tid & 63;
  int lr = l & 15, kg = l >> 4;
  int srcrow = list[min(rowbase + lr, n - 1)];
  const float* ha = hidden + (size_t)srcrow * D + kg * 8;
  for (int t = w; t < KC / 16; t += 4) {
    const unsigned short* pb = pbf + (size_t)(t * 16 + lr) * D + kg * 8;
    f32x4 acc = {0.f, 0.f, 0.f, 0.f};
    for (int kc = 0; kc < D / 32; ++kc) {
      float4 h0 = *(const float4*)(ha + kc * 32);
      float4 h1 = *(const float4*)(ha + kc * 32 + 4);
      bf16x8 a;
      a[0] = f2bf(h0.x); a[1] = f2bf(h0.y); a[2] = f2bf(h0.z); a[3] = f2bf(h0.w);
      a[4] = f2bf(h1.x); a[5] = f2bf(h1.y); a[6] = f2bf(h1.z); a[7] = f2bf(h1.w);
      bf16x8 b = *(const bf16x8*)(pb + kc * 32);
      acc = __builtin_amdgcn_mfma_f32_16x16x32_bf16(a, b, acc, 0, 0, 0);
    }
    int col = t * 16 + lr;
    for (int v = 0; v < 4; ++v) {
      int idx = rowbase + kg * 4 + v;
      if (idx < n) z[(size_t)idx * KC + col] = f2bf(acc[v]);
    }
  }
}

// ---------------- head: 64 rows x 8 waves, swizzled LDS A ------------------

__global__ __launch_bounds__(512) void head2_k(const float* __restrict__ hidden,
    const unsigned short* __restrict__ hwbf, float* __restrict__ hs_part) {
  __shared__ char Ab[64 * 2048];            // 128 KB swizzled bf16
  __shared__ float red[8][64];
  int rb = blockIdx.x >> 2, slice = blockIdx.x & 3;
  int tid = threadIdx.x;

  // stage 64 rows of hidden (fp32 -> bf16, XOR-swizzled)
  const float4* h4 = (const float4*)hidden;
#pragma unroll
  for (int j = 0; j < 16; ++j) {
    int c = j * 512 + tid;                  // 8192 16B chunks
    int row = c >> 7, k8 = c & 127;
    size_t fo = (size_t)(rb * 64 + row) * (D / 4) + k8 * 2;
    float4 f0 = h4[fo], f1 = h4[fo + 1];
    bf16x8 o;
    o[0] = f2bf(f0.x); o[1] = f2bf(f0.y); o[2] = f2bf(f0.z); o[3] = f2bf(f0.w);
    o[4] = f2bf(f1.x); o[5] = f2bf(f1.y); o[6] = f2bf(f1.z); o[7] = f2bf(f1.w);
    int addr = (row * 2048 + k8 * 16) ^ ((row & 7) << 4);
    *(bf16x8*)(Ab + addr) = o;
  }
  __syncthreads();

  int w = tid >> 6, l = tid & 63, lr = l & 15, kg = l >> 4;
  int tg0 = (slice * 8 + w) * 4;            // this wave's 4 col-tiles
  f32x4 zero4 = {0.f, 0.f, 0.f, 0.f};
  f32x4 acc[4][4];                          // [rowgroup][tile]
#pragma unroll
  for (int rg = 0; rg < 4; ++rg)
#pragma unroll
    for (int t = 0; t < 4; ++t) acc[rg][t] = zero4;

#pragma unroll 4
  for (int kc = 0; kc < 32; ++kc) {
    bf16x8 af[4], bf[4];
#pragma unroll
    for (int rg = 0; rg < 4; ++rg) {
      int addr = ((rg * 16 + lr) * 2048 + kc * 64 + kg * 16) ^ ((lr & 7) << 4);
      af[rg] = *(const bf16x8*)(Ab + addr);
    }
#pragma unroll
    for (int t = 0; t < 4; ++t)
      bf[t] = *(const bf16x8*)(hwbf + (size_t)((tg0 + t) * 16 + lr) * D + kc * 32 + kg * 8);
#pragma unroll
    for (int rg = 0; rg < 4; ++rg)
#pragma unroll
      for (int t = 0; t < 4; ++t)
        acc[rg][t] = __builtin_amdgcn_mfma_f32_16x16x32_bf16(af[rg], bf[t], acc[rg][t], 0, 0, 0);
  }

  // epilogue: sum exp2 over this wave's 64 cols
  float sv[4][4];
#pragma unroll
  for (int rg = 0; rg < 4; ++rg)
#pragma unroll
    for (int v = 0; v < 4; ++v) {
      float s = 0.f;
#pragma unroll
      for (int t = 0; t < 4; ++t) s += __builtin_amdgcn_exp2f(acc[rg][t][v]);
      sv[rg][v] = s;
    }
#pragma unroll
  for (int off = 1; off < 16; off <<= 1)
#pragma unroll
    for (int rg = 0; rg < 4; ++rg)
#pragma unroll
      for (int v = 0; v < 4; ++v) sv[rg][v] += __shfl_xor(sv[rg][v], off);
  if (lr == 0)
#pragma unroll
    for (int rg = 0; rg < 4; ++rg)
#pragma unroll
      for (int v = 0; v < 4; ++v) red[w][rg * 16 + kg * 4 + v] = sv[rg][v];
  __syncthreads();
  if (tid < 64) {
    float s = 0.f;
#pragma unroll
    for (int ww = 0; ww < 8; ++ww) s += red[ww][tid];
    hs_part[slice * N_ROWS + rb * 64 + tid] = s;
  }
}

// ---------------- tails: A in registers, 32 col-slices --------------------

template <int M_TILES, int K, int RPB, int SLICES>
__global__ __launch_bounds__(256) void tail2_k(const unsigned short* __restrict__ z,
    const unsigned short* __restrict__ twbf, const int* __restrict__ list,
    const int* __restrict__ cntp, float* __restrict__ ts_part) {
  constexpr int RG = RPB / 16;
  constexpr int NK = K / 32;
  constexpr int ST = (M_TILES + SLICES - 1) / SLICES;
  __shared__ float red[4][RPB];
  int n = *cntp;
  int rowblock = blockIdx.x / SLICES, slice = blockIdx.x % SLICES;
  int rowbase = rowblock * RPB;
  if (rowbase >= n) return;
  int tid = threadIdx.x, w = tid >> 6, l = tid & 63, lr = l & 15, kg = l >> 4;

  bf16x8 a[RG][NK];
#pragma unroll
  for (int rg = 0; rg < RG; ++rg) {
    int idx = min(rowbase + rg * 16 + lr, n - 1);
    const unsigned short* zp = z + (size_t)idx * K + kg * 8;
#pragma unroll
    for (int kc = 0; kc < NK; ++kc) a[rg][kc] = *(const bf16x8*)(zp + kc * 32);
  }
  float s[RG][4] = {};
  f32x4 zero4 = {0.f, 0.f, 0.f, 0.f};
  int t0 = slice * ST, t1 = min(t0 + ST, M_TILES);
#pragma unroll 2
  for (int tt = t0 + w; tt < t1; tt += 4) {
    const unsigned short* bp = twbf + (size_t)(tt * 16 + lr) * K + kg * 8;
    f32x4 acc[RG];
#pragma unroll
    for (int rg = 0; rg < RG; ++rg) acc[rg] = zero4;
#pragma unroll
    for (int kc = 0; kc < NK; ++kc) {
      bf16x8 b = *(const bf16x8*)(bp + kc * 32);
#pragma unroll
      for (int rg = 0; rg < RG; ++rg)
        acc[rg] = __builtin_amdgcn_mfma_f32_16x16x32_bf16(a[rg][kc], b, acc[rg], 0, 0, 0);
    }
#pragma unroll
    for (int rg = 0; rg < RG; ++rg)
#pragma unroll
      for (int v = 0; v < 4; ++v) s[rg][v] += __builtin_amdgcn_exp2f(acc[rg][v]);
  }
#pragma unroll
  for (int off = 1; off < 16; off <<= 1)
#pragma unroll
    for (int rg = 0; rg < RG; ++rg)
#pragma unroll
      for (int v = 0; v < 4; ++v) s[rg][v] += __shfl_xor(s[rg][v], off);
  if (lr == 0)
#pragma unroll
    for (int rg = 0; rg < RG; ++rg)
#pragma unroll
      for (int v = 0; v < 4; ++v) red[w][rg * 16 + kg * 4 + v] = s[rg][v];
  __syncthreads();
  if (tid < RPB) {
    int idx = rowbase + tid;
    if (idx < n)
      ts_part[(size_t)slice * N_ROWS + list[idx]] =
          red[0][tid] + red[1][tid] + red[2][tid] + red[3][tid];
  }
}

// ---------------- finalize ----------------

__global__ __launch_bounds__(256) void finalize_k(const float* __restrict__ hidden,
    const int* __restrict__ tgt, const float* __restrict__ head_w,
    const float* __restrict__ tail0, const float* __restrict__ tail1,
    const unsigned short* __restrict__ z0, const unsigned short* __restrict__ z1,
    const int* __restrict__ pos, const float* __restrict__ hs_part,
    const float* __restrict__ ts0_part, const float* __restrict__ ts1_part,
    float* __restrict__ out) {
  int w = threadIdx.x >> 6, l = threadIdx.x & 63;
  int row = blockIdx.x * 4 + w;
  int t = tgt[row];
  int jt = t < 0 ? 0 : (t < CUT0 ? t : (t < CUT1 ? CUT0 : CUT0 + 1));
  const float4* h4 = (const float4*)(hidden + (size_t)row * D);
  const float4* w4 = (const float4*)(head_w + (size_t)jt * D);
  float acc = 0.f;
#pragma unroll
  for (int j = 0; j < 4; ++j) {
    float4 a = h4[l + 64 * j], b = w4[l + 64 * j];
    acc += a.x * b.x + a.y * b.y + a.z * b.z + a.w * b.w;
  }
  float hp = (l < 4) ? hs_part[l * N_ROWS + row] : 0.f;
#pragma unroll
  for (int off = 32; off; off >>= 1) {
    acc += __shfl_xor(acc, off);
    hp  += __shfl_xor(hp, off);
  }
  float val = acc - __logf(hp - 46.f);      // subtract 46 zero-pad cols
  if (t >= CUT0) {
    int p = pos[row];
    float ta = 0.f;
    if (t < CUT1) {
      const unsigned short* zr = z0 + (size_t)p * 256;
      const float* tw = tail0 + (size_t)(t - CUT0) * 256;
#pragma unroll
      for (int j = 0; j < 4; ++j) ta += bf2f(zr[l + 64 * j]) * tw[l + 64 * j];
    } else {
      const unsigned short* zr = z1 + (size_t)p * 64;
      const float* tw = tail1 + (size_t)(t - CUT1) * 64;
      ta = bf2f(zr[l]) * tw[l];
    }
    const float* tsp = (t < CUT1) ? ts0_part : ts1_part;
    float tp = (l < 32) ? tsp[(size_t)l * N_ROWS + row] : 0.f;
#pragma unroll
    for (int off = 32; off; off >>= 1) {
      ta += __shfl_xor(ta, off);
      tp += __shfl_xor(tp, off);
    }
    float lt = tp - ((t >= CUT1) ? 15.f : 0.f);  // subtract zero-pad cols
    val += ta - __logf(lt);
  }
  if (l == 0) out[row] = (t < 0) ? 0.f : val;
}

// ---------------- loss ----------------

__global__ __launch_bounds__(256) void loss_k(const float* __restrict__ out,
                                              const int* __restrict__ target,
                                              float* __restrict__ loss) {
  __shared__ float ssum[256];
  __shared__ int scnt[256];
  float s = 0.f; int c = 0;
  for (int i = threadIdx.x; i < N_ROWS; i += 256) {
    s += out[i];
    if (target[i] >= 0) c++;
  }
  ssum[threadIdx.x] = s; scnt[threadIdx.x] = c;
  __syncthreads();
  for (int off = 128; off; off >>= 1) {
    if (threadIdx.x < off) {
      ssum[threadIdx.x] += ssum[threadIdx.x + off];
      scnt[threadIdx.x] += scnt[threadIdx.x + off];
    }
    __syncthreads();
  }
  if (threadIdx.x == 0) {
    int nv = scnt[0];
    loss[0] = (nv > 0) ? (-ssum[0] / (float)nv) : 0.f;
  }
}

// ---------------- launch ----------------

extern "C" void kernel_launch(void* const* d_in, const int* in_sizes, int n_in,
                              void* d_out, int out_size, void* d_ws, size_t ws_size,
                              hipStream_t stream) {
  const float* hidden = (const float*)d_in[0];
  const int*   target = (const int*)d_in[1];
  const float* head_w = (const float*)d_in[2];
  const float* proj0  = (const float*)d_in[3];
  const float* tail0  = (const float*)d_in[4];
  const float* proj1  = (const float*)d_in[5];
  const float* tail1  = (const float*)d_in[6];
  float* out = (float*)d_out;

  char* wp = (char*)d_ws;
  auto alloc = [&](size_t bytes) {
    char* p = wp;
    wp += (bytes + 255) & ~(size_t)255;
    return p;
  };
  int* cnt   = (int*)alloc(8);
  int* list0 = (int*)alloc(N_ROWS * 4);
  int* list1 = (int*)alloc(N_ROWS * 4);
  int* pos   = (int*)alloc(N_ROWS * 4);
  unsigned short* hwbf = (unsigned short*)alloc((size_t)HMP * D * 2);
  unsigned short* t0bf = (unsigned short*)alloc((size_t)T0MP * 256 * 2);
  unsigned short* t1bf = (unsigned short*)alloc((size_t)T1MP * 64 * 2);
  unsigned short* p0bf = (unsigned short*)alloc((size_t)256 * D * 2);
  unsigned short* p1bf = (unsigned short*)alloc((size_t)64 * D * 2);
  unsigned short* z0   = (unsigned short*)alloc((size_t)N_ROWS * 256 * 2);
  unsigned short* z1   = (unsigned short*)alloc((size_t)N_ROWS * 64 * 2);
  float* hs_part  = (float*)alloc((size_t)4 * N_ROWS * 4);
  float* ts0_part = (float*)alloc((size_t)32 * N_ROWS * 4);
  float* ts1_part = (float*)alloc((size_t)32 * N_ROWS * 4);

  zero2_k<<<1, 1, 0, stream>>>(cnt);
  classify_k<<<N_ROWS / 256, 256, 0, stream>>>(target, cnt, list0, list1, pos);
  auto cgrid = [](size_t cap) { return (int)((cap / 4 + 255) / 256); };
  convert_k<<<cgrid((size_t)HMP * D), 256, 0, stream>>>(head_w, hwbf, HM * D, HMP * D, LOG2E);
  convert_k<<<cgrid((size_t)T0MP * 256), 256, 0, stream>>>(tail0, t0bf, T0M * 256, T0MP * 256, LOG2E);
  convert_k<<<cgrid((size_t)T1MP * 64), 256, 0, stream>>>(tail1, t1bf, T1M * 64, T1MP * 64, LOG2E);
  convert_k<<<cgrid((size_t)256 * D), 256, 0, stream>>>(proj0, p0bf, 256 * D, 256 * D, 1.0f);
  convert_k<<<cgrid((size_t)64 * D), 256, 0, stream>>>(proj1, p1bf, 64 * D, 64 * D, 1.0f);
  z_k<256><<<N_ROWS / 16, 256, 0, stream>>>(hidden, p0bf, list0, cnt + 0, z0);
  z_k<64><<<N_ROWS / 16, 256, 0, stream>>>(hidden, p1bf, list1, cnt + 1, z1);
  head2_k<<<(N_ROWS / 64) * 4, 512, 0, stream>>>(hidden, hwbf, hs_part);
  tail2_k<T0MP / 16, 256, 32, 32><<<(N_ROWS / 32) * 32, 256, 0, stream>>>(z0, t0bf, list0, cnt + 0, ts0_part);
  tail2_k<T1MP / 16, 64, 128, 32><<<(N_ROWS / 128) * 32, 256, 0, stream>>>(z1, t1bf, list1, cnt + 1, ts1_part);
  finalize_k<<<N_ROWS / 4, 256, 0, stream>>>(hidden, target, head_w, tail0, tail1,
                                             z0, z1, pos, hs_part, ts0_part, ts1_part, out);
  loss_k<<<1, 256, 0, stream>>>(out, target, out + N_ROWS);
}

// Round 4
// 154.445 us; speedup vs baseline: 18.6683x; 1.5656x over previous
//
#include <hip/hip_runtime.h>
#include <math.h>

using f32x4  = __attribute__((ext_vector_type(4))) float;
using bf16x8 = __attribute__((ext_vector_type(8))) short;

namespace {
constexpr int N_ROWS = 4096;
constexpr int D      = 1024;
constexpr int CUT0   = 2000, CUT1 = 10000, VTOT = 50257;
constexpr int HM   = 2002;                 // head cols (2000 + 2 cluster)
constexpr int HMP  = 2048;                 // padded head cols (pad = 46)
constexpr int T0M  = 8000,              T0MP = 8000;    // pad 0
constexpr int T1M  = VTOT - CUT1;                        // 40257
constexpr int T1MP = 40272;                              // pad 15
constexpr float LOG2E = 1.4426950408889634f;
// fused-convert region boundaries (in elements)
constexpr long long B0 = (long long)HMP * D;             // head
constexpr long long B1 = B0 + (long long)T0MP * 256;     // tail0
constexpr long long B2 = B1 + (long long)T1MP * 64;      // tail1
constexpr long long B3 = B2 + (long long)256 * D;        // proj0
constexpr long long B4 = B3 + (long long)64 * D;         // proj1
}

__device__ __forceinline__ unsigned short f2bf(float x) {
  unsigned u = __builtin_bit_cast(unsigned, x);
  u += 0x7FFFu + ((u >> 16) & 1u);
  return (unsigned short)(u >> 16);
}
__device__ __forceinline__ float bf2f(unsigned short b) {
  unsigned u = ((unsigned)b) << 16;
  return __builtin_bit_cast(float, u);
}

// ---------------- single-block scan: compaction without atomics -----------

__global__ __launch_bounds__(256) void scan_k(const int* __restrict__ tgt,
    int* __restrict__ cnt, int* __restrict__ l0, int* __restrict__ l1,
    int* __restrict__ pos) {
  __shared__ int s0[256], s1[256];
  int tid = threadIdx.x;
  int c0 = 0, c1 = 0;
#pragma unroll
  for (int j = 0; j < 16; ++j) {
    int v = tgt[tid * 16 + j];
    c0 += (v >= CUT0 && v < CUT1);
    c1 += (v >= CUT1);
  }
  s0[tid] = c0; s1[tid] = c1;
  __syncthreads();
  for (int off = 1; off < 256; off <<= 1) {
    int a0 = (tid >= off) ? s0[tid - off] : 0;
    int a1 = (tid >= off) ? s1[tid - off] : 0;
    __syncthreads();
    s0[tid] += a0; s1[tid] += a1;
    __syncthreads();
  }
  int b0 = s0[tid] - c0, b1 = s1[tid] - c1;
#pragma unroll
  for (int j = 0; j < 16; ++j) {
    int row = tid * 16 + j;
    int v = tgt[row];
    if (v >= CUT0 && v < CUT1) { l0[b0] = row; pos[row] = b0; ++b0; }
    else if (v >= CUT1)        { l1[b1] = row; pos[row] = b1; ++b1; }
  }
  if (tid == 255) { cnt[0] = s0[255]; cnt[1] = s1[255]; }
}

// ---------------- fused fp32->bf16 convert of all weight tensors ----------

__global__ __launch_bounds__(256) void convert_all_k(
    const float* __restrict__ hw, const float* __restrict__ t0,
    const float* __restrict__ t1, const float* __restrict__ p0,
    const float* __restrict__ p1, unsigned short* __restrict__ dhw,
    unsigned short* __restrict__ dt0, unsigned short* __restrict__ dt1,
    unsigned short* __restrict__ dp0, unsigned short* __restrict__ dp1) {
  long long i = ((long long)blockIdx.x * 256 + threadIdx.x) * 4;
  if (i >= B4) return;
  const float* src; unsigned short* dst; long long off; long long nsrc;
  float scale = LOG2E;
  if (i < B0)      { src = hw; dst = dhw; off = i;      nsrc = (long long)HM * D; }
  else if (i < B1) { src = t0; dst = dt0; off = i - B0; nsrc = (long long)T0M * 256; }
  else if (i < B2) { src = t1; dst = dt1; off = i - B1; nsrc = (long long)T1M * 64; }
  else if (i < B3) { src = p0; dst = dp0; off = i - B2; nsrc = (long long)256 * D; scale = 1.f; }
  else             { src = p1; dst = dp1; off = i - B3; nsrc = (long long)64 * D;  scale = 1.f; }
  ushort4 o;
  if (off < nsrc) {   // all region sizes are multiples of 4
    float4 f = *(const float4*)(src + off);
    o.x = f2bf(f.x * scale); o.y = f2bf(f.y * scale);
    o.z = f2bf(f.z * scale); o.w = f2bf(f.w * scale);
  } else {
    o.x = o.y = o.z = o.w = 0;
  }
  *(ushort4*)(dst + off) = o;
}

// ---------------- z = gather(hidden) @ proj^T : 8 waves, K-split ----------

template <int KC, int TPB>   // TPB: col-tiles per block (8 for z0, 4 for z1)
__global__ __launch_bounds__(512) void z2_k(const float* __restrict__ hidden,
    const unsigned short* __restrict__ pbf, const int* __restrict__ list,
    const int* __restrict__ cntp, unsigned short* __restrict__ z) {
  constexpr int NBPR = (KC / 16) / TPB;   // col-blocks per row-tile
  constexpr int TPW  = TPB / 4;           // tiles per wave
  __shared__ f32x4 part[TPB][64];
  int n = *cntp;
  int rowtile = blockIdx.x / NBPR, colblk = blockIdx.x % NBPR;
  int rowbase = rowtile * 16;
  if (rowbase >= n) return;
  int tid = threadIdx.x, w = tid >> 6, l = tid & 63, lr = l & 15, kg = l >> 4;
  int kq = w >> 2, cw = w & 3;            // K-half, col-wave

  int srcrow = list[min(rowbase + lr, n - 1)];
  const float* ha = hidden + (size_t)srcrow * D + kq * 512 + kg * 8;
  bf16x8 a[16];
#pragma unroll
  for (int s = 0; s < 16; ++s) {
    float4 h0 = *(const float4*)(ha + s * 32);
    float4 h1 = *(const float4*)(ha + s * 32 + 4);
    bf16x8 t;
    t[0] = f2bf(h0.x); t[1] = f2bf(h0.y); t[2] = f2bf(h0.z); t[3] = f2bf(h0.w);
    t[4] = f2bf(h1.x); t[5] = f2bf(h1.y); t[6] = f2bf(h1.z); t[7] = f2bf(h1.w);
    a[s] = t;
  }
  f32x4 accs[TPW];
#pragma unroll
  for (int ti = 0; ti < TPW; ++ti) {
    int tt = cw + ti * 4;
    int col = (colblk * TPB + tt) * 16 + lr;
    const unsigned short* pb = pbf + (size_t)col * D + kq * 512 + kg * 8;
    f32x4 acc = {0.f, 0.f, 0.f, 0.f};
#pragma unroll
    for (int s = 0; s < 16; ++s) {
      bf16x8 b = *(const bf16x8*)(pb + s * 32);
      acc = __builtin_amdgcn_mfma_f32_16x16x32_bf16(a[s], b, acc, 0, 0, 0);
    }
    if (kq == 1) part[tt][l] = acc; else accs[ti] = acc;
  }
  __syncthreads();
  if (kq == 0) {
#pragma unroll
    for (int ti = 0; ti < TPW; ++ti) {
      int tt = cw + ti * 4;
      f32x4 p = part[tt][l];
      int col = (colblk * TPB + tt) * 16 + lr;
#pragma unroll
      for (int v = 0; v < 4; ++v) {
        int idx = rowbase + kg * 4 + v;
        if (idx < n) z[(size_t)idx * KC + col] = f2bf(accs[ti][v] + p[v]);
      }
    }
  }
}

// ---------------- head: 64 rows x 8 waves, swizzled LDS A ------------------

__global__ __launch_bounds__(512) void head2_k(const float* __restrict__ hidden,
    const unsigned short* __restrict__ hwbf, float* __restrict__ hs_part) {
  __shared__ char Ab[64 * 2048];            // 128 KB swizzled bf16
  __shared__ float red[8][64];
  int rb = blockIdx.x >> 2, slice = blockIdx.x & 3;
  int tid = threadIdx.x;

  const float4* h4 = (const float4*)hidden;
#pragma unroll
  for (int j = 0; j < 16; ++j) {
    int c = j * 512 + tid;                  // 8192 16B chunks
    int row = c >> 7, k8 = c & 127;
    size_t fo = (size_t)(rb * 64 + row) * (D / 4) + k8 * 2;
    float4 f0 = h4[fo], f1 = h4[fo + 1];
    bf16x8 o;
    o[0] = f2bf(f0.x); o[1] = f2bf(f0.y); o[2] = f2bf(f0.z); o[3] = f2bf(f0.w);
    o[4] = f2bf(f1.x); o[5] = f2bf(f1.y); o[6] = f2bf(f1.z); o[7] = f2bf(f1.w);
    int addr = (row * 2048 + k8 * 16) ^ ((row & 7) << 4);
    *(bf16x8*)(Ab + addr) = o;
  }
  __syncthreads();

  int w = tid >> 6, l = tid & 63, lr = l & 15, kg = l >> 4;
  int tg0 = (slice * 8 + w) * 4;            // this wave's 4 col-tiles
  f32x4 zero4 = {0.f, 0.f, 0.f, 0.f};
  f32x4 acc[4][4];                          // [rowgroup][tile]
#pragma unroll
  for (int rg = 0; rg < 4; ++rg)
#pragma unroll
    for (int t = 0; t < 4; ++t) acc[rg][t] = zero4;

#pragma unroll 4
  for (int kc = 0; kc < 32; ++kc) {
    bf16x8 af[4], bf[4];
#pragma unroll
    for (int rg = 0; rg < 4; ++rg) {
      int addr = ((rg * 16 + lr) * 2048 + kc * 64 + kg * 16) ^ ((lr & 7) << 4);
      af[rg] = *(const bf16x8*)(Ab + addr);
    }
#pragma unroll
    for (int t = 0; t < 4; ++t)
      bf[t] = *(const bf16x8*)(hwbf + (size_t)((tg0 + t) * 16 + lr) * D + kc * 32 + kg * 8);
#pragma unroll
    for (int rg = 0; rg < 4; ++rg)
#pragma unroll
      for (int t = 0; t < 4; ++t)
        acc[rg][t] = __builtin_amdgcn_mfma_f32_16x16x32_bf16(af[rg], bf[t], acc[rg][t], 0, 0, 0);
  }

  float sv[4][4];
#pragma unroll
  for (int rg = 0; rg < 4; ++rg)
#pragma unroll
    for (int v = 0; v < 4; ++v) {
      float s = 0.f;
#pragma unroll
      for (int t = 0; t < 4; ++t) s += __builtin_amdgcn_exp2f(acc[rg][t][v]);
      sv[rg][v] = s;
    }
#pragma unroll
  for (int off = 1; off < 16; off <<= 1)
#pragma unroll
    for (int rg = 0; rg < 4; ++rg)
#pragma unroll
      for (int v = 0; v < 4; ++v) sv[rg][v] += __shfl_xor(sv[rg][v], off);
  if (lr == 0)
#pragma unroll
    for (int rg = 0; rg < 4; ++rg)
#pragma unroll
      for (int v = 0; v < 4; ++v) red[w][rg * 16 + kg * 4 + v] = sv[rg][v];
  __syncthreads();
  if (tid < 64) {
    float s = 0.f;
#pragma unroll
    for (int ww = 0; ww < 8; ++ww) s += red[ww][tid];
    hs_part[slice * N_ROWS + rb * 64 + tid] = s;
  }
}

// ---------------- tails: A in registers, 32 col-slices --------------------

template <int M_TILES, int K, int RPB, int SLICES>
__global__ __launch_bounds__(256) void tail2_k(const unsigned short* __restrict__ z,
    const unsigned short* __restrict__ twbf, const int* __restrict__ list,
    const int* __restrict__ cntp, float* __restrict__ ts_part) {
  constexpr int RG = RPB / 16;
  constexpr int NK = K / 32;
  constexpr int ST = (M_TILES + SLICES - 1) / SLICES;
  __shared__ float red[4][RPB];
  int n = *cntp;
  int rowblock = blockIdx.x / SLICES, slice = blockIdx.x % SLICES;
  int rowbase = rowblock * RPB;
  if (rowbase >= n) return;
  int tid = threadIdx.x, w = tid >> 6, l = tid & 63, lr = l & 15, kg = l >> 4;

  bf16x8 a[RG][NK];
#pragma unroll
  for (int rg = 0; rg < RG; ++rg) {
    int idx = min(rowbase + rg * 16 + lr, n - 1);
    const unsigned short* zp = z + (size_t)idx * K + kg * 8;
#pragma unroll
    for (int kc = 0; kc < NK; ++kc) a[rg][kc] = *(const bf16x8*)(zp + kc * 32);
  }
  float s[RG][4] = {};
  f32x4 zero4 = {0.f, 0.f, 0.f, 0.f};
  int t0 = slice * ST, t1 = min(t0 + ST, M_TILES);
#pragma unroll 2
  for (int tt = t0 + w; tt < t1; tt += 4) {
    const unsigned short* bp = twbf + (size_t)(tt * 16 + lr) * K + kg * 8;
    f32x4 acc[RG];
#pragma unroll
    for (int rg = 0; rg < RG; ++rg) acc[rg] = zero4;
#pragma unroll
    for (int kc = 0; kc < NK; ++kc) {
      bf16x8 b = *(const bf16x8*)(bp + kc * 32);
#pragma unroll
      for (int rg = 0; rg < RG; ++rg)
        acc[rg] = __builtin_amdgcn_mfma_f32_16x16x32_bf16(a[rg][kc], b, acc[rg], 0, 0, 0);
    }
#pragma unroll
    for (int rg = 0; rg < RG; ++rg)
#pragma unroll
      for (int v = 0; v < 4; ++v) s[rg][v] += __builtin_amdgcn_exp2f(acc[rg][v]);
  }
#pragma unroll
  for (int off = 1; off < 16; off <<= 1)
#pragma unroll
    for (int rg = 0; rg < RG; ++rg)
#pragma unroll
      for (int v = 0; v < 4; ++v) s[rg][v] += __shfl_xor(s[rg][v], off);
  if (lr == 0)
#pragma unroll
    for (int rg = 0; rg < RG; ++rg)
#pragma unroll
      for (int v = 0; v < 4; ++v) red[w][rg * 16 + kg * 4 + v] = s[rg][v];
  __syncthreads();
  if (tid < RPB) {
    int idx = rowbase + tid;
    if (idx < n)
      ts_part[(size_t)slice * N_ROWS + list[idx]] =
          red[0][tid] + red[1][tid] + red[2][tid] + red[3][tid];
  }
}

// ---------------- finalize ----------------

__global__ __launch_bounds__(256) void finalize_k(const float* __restrict__ hidden,
    const int* __restrict__ tgt, const float* __restrict__ head_w,
    const float* __restrict__ tail0, const float* __restrict__ tail1,
    const unsigned short* __restrict__ z0, const unsigned short* __restrict__ z1,
    const int* __restrict__ pos, const float* __restrict__ hs_part,
    const float* __restrict__ ts0_part, const float* __restrict__ ts1_part,
    float* __restrict__ out) {
  int w = threadIdx.x >> 6, l = threadIdx.x & 63;
  int row = blockIdx.x * 4 + w;
  int t = tgt[row];
  int jt = t < 0 ? 0 : (t < CUT0 ? t : (t < CUT1 ? CUT0 : CUT0 + 1));
  const float4* h4 = (const float4*)(hidden + (size_t)row * D);
  const float4* w4 = (const float4*)(head_w + (size_t)jt * D);
  float acc = 0.f;
#pragma unroll
  for (int j = 0; j < 4; ++j) {
    float4 a = h4[l + 64 * j], b = w4[l + 64 * j];
    acc += a.x * b.x + a.y * b.y + a.z * b.z + a.w * b.w;
  }
  float hp = (l < 4) ? hs_part[l * N_ROWS + row] : 0.f;
#pragma unroll
  for (int off = 32; off; off >>= 1) {
    acc += __shfl_xor(acc, off);
    hp  += __shfl_xor(hp, off);
  }
  float val = acc - __logf(hp - 46.f);      // subtract 46 zero-pad cols
  if (t >= CUT0) {
    int p = pos[row];
    float ta = 0.f;
    if (t < CUT1) {
      const unsigned short* zr = z0 + (size_t)p * 256;
      const float* tw = tail0 + (size_t)(t - CUT0) * 256;
#pragma unroll
      for (int j = 0; j < 4; ++j) ta += bf2f(zr[l + 64 * j]) * tw[l + 64 * j];
    } else {
      const unsigned short* zr = z1 + (size_t)p * 64;
      const float* tw = tail1 + (size_t)(t - CUT1) * 64;
      ta = bf2f(zr[l]) * tw[l];
    }
    const float* tsp = (t < CUT1) ? ts0_part : ts1_part;
    float tp = (l < 32) ? tsp[(size_t)l * N_ROWS + row] : 0.f;
#pragma unroll
    for (int off = 32; off; off >>= 1) {
      ta += __shfl_xor(ta, off);
      tp += __shfl_xor(tp, off);
    }
    float lt = tp - ((t >= CUT1) ? 15.f : 0.f);  // subtract zero-pad cols
    val += ta - __logf(lt);
  }
  if (l == 0) out[row] = (t < 0) ? 0.f : val;
}

// ---------------- loss ----------------

__global__ __launch_bounds__(256) void loss_k(const float* __restrict__ out,
                                              const int* __restrict__ target,
                                              float* __restrict__ loss) {
  __shared__ float ssum[256];
  __shared__ int scnt[256];
  float s = 0.f; int c = 0;
  for (int i = threadIdx.x; i < N_ROWS; i += 256) {
    s += out[i];
    if (target[i] >= 0) c++;
  }
  ssum[threadIdx.x] = s; scnt[threadIdx.x] = c;
  __syncthreads();
  for (int off = 128; off; off >>= 1) {
    if (threadIdx.x < off) {
      ssum[threadIdx.x] += ssum[threadIdx.x + off];
      scnt[threadIdx.x] += scnt[threadIdx.x + off];
    }
    __syncthreads();
  }
  if (threadIdx.x == 0) {
    int nv = scnt[0];
    loss[0] = (nv > 0) ? (-ssum[0] / (float)nv) : 0.f;
  }
}

// ---------------- launch ----------------

extern "C" void kernel_launch(void* const* d_in, const int* in_sizes, int n_in,
                              void* d_out, int out_size, void* d_ws, size_t ws_size,
                              hipStream_t stream) {
  const float* hidden = (const float*)d_in[0];
  const int*   target = (const int*)d_in[1];
  const float* head_w = (const float*)d_in[2];
  const float* proj0  = (const float*)d_in[3];
  const float* tail0  = (const float*)d_in[4];
  const float* proj1  = (const float*)d_in[5];
  const float* tail1  = (const float*)d_in[6];
  float* out = (float*)d_out;

  char* wp = (char*)d_ws;
  auto alloc = [&](size_t bytes) {
    char* p = wp;
    wp += (bytes + 255) & ~(size_t)255;
    return p;
  };
  int* cnt   = (int*)alloc(8);
  int* list0 = (int*)alloc(N_ROWS * 4);
  int* list1 = (int*)alloc(N_ROWS * 4);
  int* pos   = (int*)alloc(N_ROWS * 4);
  unsigned short* hwbf = (unsigned short*)alloc((size_t)HMP * D * 2);
  unsigned short* t0bf = (unsigned short*)alloc((size_t)T0MP * 256 * 2);
  unsigned short* t1bf = (unsigned short*)alloc((size_t)T1MP * 64 * 2);
  unsigned short* p0bf = (unsigned short*)alloc((size_t)256 * D * 2);
  unsigned short* p1bf = (unsigned short*)alloc((size_t)64 * D * 2);
  unsigned short* z0   = (unsigned short*)alloc((size_t)N_ROWS * 256 * 2);
  unsigned short* z1   = (unsigned short*)alloc((size_t)N_ROWS * 64 * 2);
  float* hs_part  = (float*)alloc((size_t)4 * N_ROWS * 4);
  float* ts0_part = (float*)alloc((size_t)32 * N_ROWS * 4);
  float* ts1_part = (float*)alloc((size_t)32 * N_ROWS * 4);

  scan_k<<<1, 256, 0, stream>>>(target, cnt, list0, list1, pos);
  convert_all_k<<<(int)((B4 / 4 + 255) / 256), 256, 0, stream>>>(
      head_w, tail0, tail1, proj0, proj1, hwbf, t0bf, t1bf, p0bf, p1bf);
  head2_k<<<(N_ROWS / 64) * 4, 512, 0, stream>>>(hidden, hwbf, hs_part);
  z2_k<256, 8><<<(N_ROWS / 16) * 2, 512, 0, stream>>>(hidden, p0bf, list0, cnt + 0, z0);
  z2_k<64, 4><<<(N_ROWS / 16) * 1, 512, 0, stream>>>(hidden, p1bf, list1, cnt + 1, z1);
  tail2_k<T0MP / 16, 256, 32, 32><<<(N_ROWS / 32) * 32, 256, 0, stream>>>(z0, t0bf, list0, cnt + 0, ts0_part);
  tail2_k<T1MP / 16, 64, 128, 32><<<(N_ROWS / 128) * 32, 256, 0, stream>>>(z1, t1bf, list1, cnt + 1, ts1_part);
  finalize_k<<<N_ROWS / 4, 256, 0, stream>>>(hidden, target, head_w, tail0, tail1,
                                             z0, z1, pos, hs_part, ts0_part, ts1_part, out);
  loss_k<<<1, 256, 0, stream>>>(out, target, out + N_ROWS);
}

// Round 5
// 143.375 us; speedup vs baseline: 20.1097x; 1.0772x over previous
//
#include <hip/hip_runtime.h>
#include <math.h>

using f32x4  = __attribute__((ext_vector_type(4))) float;
using bf16x8 = __attribute__((ext_vector_type(8))) short;

namespace {
constexpr int N_ROWS = 4096;
constexpr int D      = 1024;
constexpr int CUT0   = 2000, CUT1 = 10000, VTOT = 50257;
constexpr int HM   = 2002;                 // head cols (2000 + 2 cluster)
constexpr int HMP  = 2048;                 // padded head cols (pad = 46)
constexpr int T0M  = 8000,              T0MP = 8000;    // pad 0
constexpr int T1M  = VTOT - CUT1;                        // 40257
constexpr int T1MP = 40272;                              // pad 15
constexpr float LOG2E = 1.4426950408889634f;
// fused-convert region boundaries (weights, in elements)
constexpr long long B0 = (long long)HMP * D;             // head
constexpr long long B1 = B0 + (long long)T0MP * 256;     // tail0
constexpr long long B2 = B1 + (long long)T1MP * 64;      // tail1
constexpr long long B3 = B2 + (long long)256 * D;        // proj0
constexpr long long B4 = B3 + (long long)64 * D;         // proj1
}

__device__ __forceinline__ unsigned short f2bf(float x) {
  unsigned u = __builtin_bit_cast(unsigned, x);
  u += 0x7FFFu + ((u >> 16) & 1u);
  return (unsigned short)(u >> 16);
}
__device__ __forceinline__ float bf2f(unsigned short b) {
  unsigned u = ((unsigned)b) << 16;
  return __builtin_bit_cast(float, u);
}

// ---------------- single-block scan: compaction without atomics -----------

__global__ __launch_bounds__(256) void scan_k(const int* __restrict__ tgt,
    int* __restrict__ cnt, int* __restrict__ l0, int* __restrict__ l1,
    int* __restrict__ pos) {
  __shared__ int s0[256], s1[256];
  int tid = threadIdx.x;
  int c0 = 0, c1 = 0;
#pragma unroll
  for (int j = 0; j < 16; ++j) {
    int v = tgt[tid * 16 + j];
    c0 += (v >= CUT0 && v < CUT1);
    c1 += (v >= CUT1);
  }
  s0[tid] = c0; s1[tid] = c1;
  __syncthreads();
  for (int off = 1; off < 256; off <<= 1) {
    int a0 = (tid >= off) ? s0[tid - off] : 0;
    int a1 = (tid >= off) ? s1[tid - off] : 0;
    __syncthreads();
    s0[tid] += a0; s1[tid] += a1;
    __syncthreads();
  }
  int b0 = s0[tid] - c0, b1 = s1[tid] - c1;
#pragma unroll
  for (int j = 0; j < 16; ++j) {
    int row = tid * 16 + j;
    int v = tgt[row];
    if (v >= CUT0 && v < CUT1) { l0[b0] = row; pos[row] = b0; ++b0; }
    else if (v >= CUT1)        { l1[b1] = row; pos[row] = b1; ++b1; }
  }
  if (tid == 255) { cnt[0] = s0[255]; cnt[1] = s1[255]; }
}

// ------- hidden fp32 -> bf16, stored as swizzled 64-row LDS tile images ----

__global__ __launch_bounds__(256) void converth_k(const float* __restrict__ hidden,
                                                  unsigned short* __restrict__ hbf) {
  int c = blockIdx.x * 256 + threadIdx.x;        // 16B chunk id (8 elems)
  int row = c >> 7, k8 = c & 127;
  float4 f0 = *(const float4*)(hidden + (size_t)row * D + k8 * 8);
  float4 f1 = *(const float4*)(hidden + (size_t)row * D + k8 * 8 + 4);
  bf16x8 o;
  o[0] = f2bf(f0.x); o[1] = f2bf(f0.y); o[2] = f2bf(f0.z); o[3] = f2bf(f0.w);
  o[4] = f2bf(f1.x); o[5] = f2bf(f1.y); o[6] = f2bf(f1.z); o[7] = f2bf(f1.w);
  size_t tb = (size_t)(row >> 6) * 131072;       // 128 KB per 64-row tile
  int boff = (((row & 63) * 2048 + k8 * 16) ^ ((row & 7) << 4));
  *(bf16x8*)((char*)hbf + tb + boff) = o;
}

// ---------------- fused fp32->bf16 convert of all weight tensors ----------

__global__ __launch_bounds__(256) void convert_all_k(
    const float* __restrict__ hw, const float* __restrict__ t0,
    const float* __restrict__ t1, const float* __restrict__ p0,
    const float* __restrict__ p1, unsigned short* __restrict__ dhw,
    unsigned short* __restrict__ dt0, unsigned short* __restrict__ dt1,
    unsigned short* __restrict__ dp0, unsigned short* __restrict__ dp1) {
  long long i = ((long long)blockIdx.x * 256 + threadIdx.x) * 4;
  if (i >= B4) return;
  const float* src; unsigned short* dst; long long off; long long nsrc;
  float scale = LOG2E;
  if (i < B0)      { src = hw; dst = dhw; off = i;      nsrc = (long long)HM * D; }
  else if (i < B1) { src = t0; dst = dt0; off = i - B0; nsrc = (long long)T0M * 256; }
  else if (i < B2) { src = t1; dst = dt1; off = i - B1; nsrc = (long long)T1M * 64; }
  else if (i < B3) { src = p0; dst = dp0; off = i - B2; nsrc = (long long)256 * D; scale = 1.f; }
  else             { src = p1; dst = dp1; off = i - B3; nsrc = (long long)64 * D;  scale = 1.f; }
  ushort4 o;
  if (off < nsrc) {   // all region sizes are multiples of 4
    float4 f = *(const float4*)(src + off);
    o.x = f2bf(f.x * scale); o.y = f2bf(f.y * scale);
    o.z = f2bf(f.z * scale); o.w = f2bf(f.w * scale);
  } else {
    o.x = o.y = o.z = o.w = 0;
  }
  *(ushort4*)(dst + off) = o;
}

// ---------------- z = gather(hbf) @ proj^T : 8 waves, K-split -------------

template <int KC, int TPB>   // TPB: col-tiles per block (8 for z0, 4 for z1)
__global__ __launch_bounds__(512) void z2_k(const unsigned short* __restrict__ hbf,
    const unsigned short* __restrict__ pbf, const int* __restrict__ list,
    const int* __restrict__ cntp, unsigned short* __restrict__ z) {
  constexpr int NBPR = (KC / 16) / TPB;   // col-blocks per row-tile
  constexpr int TPW  = TPB / 4;           // tiles per wave
  __shared__ f32x4 part[TPB][64];
  int n = *cntp;
  int rowtile = blockIdx.x / NBPR, colblk = blockIdx.x % NBPR;
  int rowbase = rowtile * 16;
  if (rowbase >= n) return;
  int tid = threadIdx.x, w = tid >> 6, l = tid & 63, lr = l & 15, kg = l >> 4;
  int kq = w >> 2, cw = w & 3;            // K-half, col-wave

  int srcrow = list[min(rowbase + lr, n - 1)];
  size_t tb = (size_t)(srcrow >> 6) * 131072;
  int r64 = srcrow & 63, sw = (srcrow & 7) << 4;
  bf16x8 a[16];
#pragma unroll
  for (int s = 0; s < 16; ++s) {
    int k8 = kq * 64 + kg + s * 4;
    int boff = ((r64 * 2048 + k8 * 16) ^ sw);
    a[s] = *(const bf16x8*)((const char*)hbf + tb + boff);
  }
  f32x4 accs[TPW];
#pragma unroll
  for (int ti = 0; ti < TPW; ++ti) {
    int tt = cw + ti * 4;
    int col = (colblk * TPB + tt) * 16 + lr;
    const unsigned short* pb = pbf + (size_t)col * D + kq * 512 + kg * 8;
    f32x4 acc = {0.f, 0.f, 0.f, 0.f};
#pragma unroll
    for (int s = 0; s < 16; ++s) {
      bf16x8 b = *(const bf16x8*)(pb + s * 32);
      acc = __builtin_amdgcn_mfma_f32_16x16x32_bf16(a[s], b, acc, 0, 0, 0);
    }
    if (kq == 1) part[tt][l] = acc; else accs[ti] = acc;
  }
  __syncthreads();
  if (kq == 0) {
#pragma unroll
    for (int ti = 0; ti < TPW; ++ti) {
      int tt = cw + ti * 4;
      f32x4 p = part[tt][l];
      int col = (colblk * TPB + tt) * 16 + lr;
#pragma unroll
      for (int v = 0; v < 4; ++v) {
        int idx = rowbase + kg * 4 + v;
        if (idx < n) z[(size_t)idx * KC + col] = f2bf(accs[ti][v] + p[v]);
      }
    }
  }
}

// ---------------- head: 64 rows x 8 waves, pre-swizzled LDS A --------------

__global__ __launch_bounds__(512) void head3_k(const unsigned short* __restrict__ hbf,
    const unsigned short* __restrict__ hwbf, float* __restrict__ hs_part) {
  __shared__ char Ab[64 * 2048];            // 128 KB swizzled bf16 (pre-baked)
  __shared__ float red[8][64];
  int rb = blockIdx.x >> 2, slice = blockIdx.x & 3;
  int tid = threadIdx.x;

  // linear copy of the pre-swizzled 128 KB tile image
  const bf16x8* src = (const bf16x8*)(hbf + (size_t)rb * 65536);
  bf16x8* dstv = (bf16x8*)Ab;
#pragma unroll
  for (int j = 0; j < 16; ++j) dstv[j * 512 + tid] = src[j * 512 + tid];
  __syncthreads();

  int w = tid >> 6, l = tid & 63, lr = l & 15, kg = l >> 4;
  int tg0 = (slice * 8 + w) * 4;            // this wave's 4 col-tiles
  f32x4 zero4 = {0.f, 0.f, 0.f, 0.f};
  f32x4 acc[4][4];                          // [rowgroup][tile]
#pragma unroll
  for (int rg = 0; rg < 4; ++rg)
#pragma unroll
    for (int t = 0; t < 4; ++t) acc[rg][t] = zero4;

#pragma unroll 4
  for (int kc = 0; kc < 32; ++kc) {
    bf16x8 af[4], bf[4];
#pragma unroll
    for (int rg = 0; rg < 4; ++rg) {
      int addr = ((rg * 16 + lr) * 2048 + kc * 64 + kg * 16) ^ ((lr & 7) << 4);
      af[rg] = *(const bf16x8*)(Ab + addr);
    }
#pragma unroll
    for (int t = 0; t < 4; ++t)
      bf[t] = *(const bf16x8*)(hwbf + (size_t)((tg0 + t) * 16 + lr) * D + kc * 32 + kg * 8);
#pragma unroll
    for (int rg = 0; rg < 4; ++rg)
#pragma unroll
      for (int t = 0; t < 4; ++t)
        acc[rg][t] = __builtin_amdgcn_mfma_f32_16x16x32_bf16(af[rg], bf[t], acc[rg][t], 0, 0, 0);
  }

  float sv[4][4];
#pragma unroll
  for (int rg = 0; rg < 4; ++rg)
#pragma unroll
    for (int v = 0; v < 4; ++v) {
      float s = 0.f;
#pragma unroll
      for (int t = 0; t < 4; ++t) s += __builtin_amdgcn_exp2f(acc[rg][t][v]);
      sv[rg][v] = s;
    }
#pragma unroll
  for (int off = 1; off < 16; off <<= 1)
#pragma unroll
    for (int rg = 0; rg < 4; ++rg)
#pragma unroll
      for (int v = 0; v < 4; ++v) sv[rg][v] += __shfl_xor(sv[rg][v], off);
  if (lr == 0)
#pragma unroll
    for (int rg = 0; rg < 4; ++rg)
#pragma unroll
      for (int v = 0; v < 4; ++v) red[w][rg * 16 + kg * 4 + v] = sv[rg][v];
  __syncthreads();
  if (tid < 64) {
    float s = 0.f;
#pragma unroll
    for (int ww = 0; ww < 8; ++ww) s += red[ww][tid];
    hs_part[slice * N_ROWS + rb * 64 + tid] = s;
  }
}

// ---------------- tails: A in registers, 32 col-slices --------------------

template <int M_TILES, int K, int RPB, int SLICES>
__global__ __launch_bounds__(256) void tail2_k(const unsigned short* __restrict__ z,
    const unsigned short* __restrict__ twbf, const int* __restrict__ list,
    const int* __restrict__ cntp, float* __restrict__ ts_part) {
  constexpr int RG = RPB / 16;
  constexpr int NK = K / 32;
  constexpr int ST = (M_TILES + SLICES - 1) / SLICES;
  __shared__ float red[4][RPB];
  int n = *cntp;
  int rowblock = blockIdx.x / SLICES, slice = blockIdx.x % SLICES;
  int rowbase = rowblock * RPB;
  if (rowbase >= n) return;
  int tid = threadIdx.x, w = tid >> 6, l = tid & 63, lr = l & 15, kg = l >> 4;

  bf16x8 a[RG][NK];
#pragma unroll
  for (int rg = 0; rg < RG; ++rg) {
    int idx = min(rowbase + rg * 16 + lr, n - 1);
    const unsigned short* zp = z + (size_t)idx * K + kg * 8;
#pragma unroll
    for (int kc = 0; kc < NK; ++kc) a[rg][kc] = *(const bf16x8*)(zp + kc * 32);
  }
  float s[RG][4] = {};
  f32x4 zero4 = {0.f, 0.f, 0.f, 0.f};
  int t0 = slice * ST, t1 = min(t0 + ST, M_TILES);
#pragma unroll 2
  for (int tt = t0 + w; tt < t1; tt += 4) {
    const unsigned short* bp = twbf + (size_t)(tt * 16 + lr) * K + kg * 8;
    f32x4 acc[RG];
#pragma unroll
    for (int rg = 0; rg < RG; ++rg) acc[rg] = zero4;
#pragma unroll
    for (int kc = 0; kc < NK; ++kc) {
      bf16x8 b = *(const bf16x8*)(bp + kc * 32);
#pragma unroll
      for (int rg = 0; rg < RG; ++rg)
        acc[rg] = __builtin_amdgcn_mfma_f32_16x16x32_bf16(a[rg][kc], b, acc[rg], 0, 0, 0);
    }
#pragma unroll
    for (int rg = 0; rg < RG; ++rg)
#pragma unroll
      for (int v = 0; v < 4; ++v) s[rg][v] += __builtin_amdgcn_exp2f(acc[rg][v]);
  }
#pragma unroll
  for (int off = 1; off < 16; off <<= 1)
#pragma unroll
    for (int rg = 0; rg < RG; ++rg)
#pragma unroll
      for (int v = 0; v < 4; ++v) s[rg][v] += __shfl_xor(s[rg][v], off);
  if (lr == 0)
#pragma unroll
    for (int rg = 0; rg < RG; ++rg)
#pragma unroll
      for (int v = 0; v < 4; ++v) red[w][rg * 16 + kg * 4 + v] = s[rg][v];
  __syncthreads();
  if (tid < RPB) {
    int idx = rowbase + tid;
    if (idx < n)
      ts_part[(size_t)slice * N_ROWS + list[idx]] =
          red[0][tid] + red[1][tid] + red[2][tid] + red[3][tid];
  }
}

// ---------------- finalize ----------------

__global__ __launch_bounds__(256) void finalize_k(const float* __restrict__ hidden,
    const int* __restrict__ tgt, const float* __restrict__ head_w,
    const float* __restrict__ tail0, const float* __restrict__ tail1,
    const unsigned short* __restrict__ z0, const unsigned short* __restrict__ z1,
    const int* __restrict__ pos, const float* __restrict__ hs_part,
    const float* __restrict__ ts0_part, const float* __restrict__ ts1_part,
    float* __restrict__ out) {
  int w = threadIdx.x >> 6, l = threadIdx.x & 63;
  int row = blockIdx.x * 4 + w;
  int t = tgt[row];
  int jt = t < 0 ? 0 : (t < CUT0 ? t : (t < CUT1 ? CUT0 : CUT0 + 1));
  const float4* h4 = (const float4*)(hidden + (size_t)row * D);
  const float4* w4 = (const float4*)(head_w + (size_t)jt * D);
  float acc = 0.f;
#pragma unroll
  for (int j = 0; j < 4; ++j) {
    float4 a = h4[l + 64 * j], b = w4[l + 64 * j];
    acc += a.x * b.x + a.y * b.y + a.z * b.z + a.w * b.w;
  }
  float hp = (l < 4) ? hs_part[l * N_ROWS + row] : 0.f;
#pragma unroll
  for (int off = 32; off; off >>= 1) {
    acc += __shfl_xor(acc, off);
    hp  += __shfl_xor(hp, off);
  }
  float val = acc - __logf(hp - 46.f);      // subtract 46 zero-pad cols
  if (t >= CUT0) {
    int p = pos[row];
    float ta = 0.f;
    if (t < CUT1) {
      const unsigned short* zr = z0 + (size_t)p * 256;
      const float* tw = tail0 + (size_t)(t - CUT0) * 256;
#pragma unroll
      for (int j = 0; j < 4; ++j) ta += bf2f(zr[l + 64 * j]) * tw[l + 64 * j];
    } else {
      const unsigned short* zr = z1 + (size_t)p * 64;
      const float* tw = tail1 + (size_t)(t - CUT1) * 64;
      ta = bf2f(zr[l]) * tw[l];
    }
    const float* tsp = (t < CUT1) ? ts0_part : ts1_part;
    float tp = (l < 32) ? tsp[(size_t)l * N_ROWS + row] : 0.f;
#pragma unroll
    for (int off = 32; off; off >>= 1) {
      ta += __shfl_xor(ta, off);
      tp += __shfl_xor(tp, off);
    }
    float lt = tp - ((t >= CUT1) ? 15.f : 0.f);  // subtract zero-pad cols
    val += ta - __logf(lt);
  }
  if (l == 0) out[row] = (t < 0) ? 0.f : val;
}

// ---------------- loss ----------------

__global__ __launch_bounds__(256) void loss_k(const float* __restrict__ out,
                                              const int* __restrict__ target,
                                              float* __restrict__ loss) {
  __shared__ float ssum[256];
  __shared__ int scnt[256];
  float s = 0.f; int c = 0;
  for (int i = threadIdx.x; i < N_ROWS; i += 256) {
    s += out[i];
    if (target[i] >= 0) c++;
  }
  ssum[threadIdx.x] = s; scnt[threadIdx.x] = c;
  __syncthreads();
  for (int off = 128; off; off >>= 1) {
    if (threadIdx.x < off) {
      ssum[threadIdx.x] += ssum[threadIdx.x + off];
      scnt[threadIdx.x] += scnt[threadIdx.x + off];
    }
    __syncthreads();
  }
  if (threadIdx.x == 0) {
    int nv = scnt[0];
    loss[0] = (nv > 0) ? (-ssum[0] / (float)nv) : 0.f;
  }
}

// ---------------- launch ----------------

extern "C" void kernel_launch(void* const* d_in, const int* in_sizes, int n_in,
                              void* d_out, int out_size, void* d_ws, size_t ws_size,
                              hipStream_t stream) {
  const float* hidden = (const float*)d_in[0];
  const int*   target = (const int*)d_in[1];
  const float* head_w = (const float*)d_in[2];
  const float* proj0  = (const float*)d_in[3];
  const float* tail0  = (const float*)d_in[4];
  const float* proj1  = (const float*)d_in[5];
  const float* tail1  = (const float*)d_in[6];
  float* out = (float*)d_out;

  char* wp = (char*)d_ws;
  auto alloc = [&](size_t bytes) {
    char* p = wp;
    wp += (bytes + 255) & ~(size_t)255;
    return p;
  };
  int* cnt   = (int*)alloc(8);
  int* list0 = (int*)alloc(N_ROWS * 4);
  int* list1 = (int*)alloc(N_ROWS * 4);
  int* pos   = (int*)alloc(N_ROWS * 4);
  unsigned short* hbf  = (unsigned short*)alloc((size_t)N_ROWS * D * 2);
  unsigned short* hwbf = (unsigned short*)alloc((size_t)HMP * D * 2);
  unsigned short* t0bf = (unsigned short*)alloc((size_t)T0MP * 256 * 2);
  unsigned short* t1bf = (unsigned short*)alloc((size_t)T1MP * 64 * 2);
  unsigned short* p0bf = (unsigned short*)alloc((size_t)256 * D * 2);
  unsigned short* p1bf = (unsigned short*)alloc((size_t)64 * D * 2);
  unsigned short* z0   = (unsigned short*)alloc((size_t)N_ROWS * 256 * 2);
  unsigned short* z1   = (unsigned short*)alloc((size_t)N_ROWS * 64 * 2);
  float* hs_part  = (float*)alloc((size_t)4 * N_ROWS * 4);
  float* ts0_part = (float*)alloc((size_t)32 * N_ROWS * 4);
  float* ts1_part = (float*)alloc((size_t)32 * N_ROWS * 4);

  scan_k<<<1, 256, 0, stream>>>(target, cnt, list0, list1, pos);
  converth_k<<<(N_ROWS * D / 8) / 256, 256, 0, stream>>>(hidden, hbf);
  convert_all_k<<<(int)((B4 / 4 + 255) / 256), 256, 0, stream>>>(
      head_w, tail0, tail1, proj0, proj1, hwbf, t0bf, t1bf, p0bf, p1bf);
  head3_k<<<(N_ROWS / 64) * 4, 512, 0, stream>>>(hbf, hwbf, hs_part);
  z2_k<256, 8><<<(N_ROWS / 16) * 2, 512, 0, stream>>>(hbf, p0bf, list0, cnt + 0, z0);
  z2_k<64, 4><<<(N_ROWS / 16) * 1, 512, 0, stream>>>(hbf, p1bf, list1, cnt + 1, z1);
  tail2_k<T0MP / 16, 256, 32, 32><<<(N_ROWS / 32) * 32, 256, 0, stream>>>(z0, t0bf, list0, cnt + 0, ts0_part);
  tail2_k<T1MP / 16, 64, 128, 32><<<(N_ROWS / 128) * 32, 256, 0, stream>>>(z1, t1bf, list1, cnt + 1, ts1_part);
  finalize_k<<<N_ROWS / 4, 256, 0, stream>>>(hidden, target, head_w, tail0, tail1,
                                             z0, z1, pos, hs_part, ts0_part, ts1_part, out);
  loss_k<<<1, 256, 0, stream>>>(out, target, out + N_ROWS);
}